// Round 4
// baseline (244.631 us; speedup 1.0000x reference)
//
#include <hip/hip_runtime.h>

#define C 128
#define G 8
#define KNN 16
#define QB 4
#define EPS 1e-5f

typedef unsigned short u16;
typedef __attribute__((ext_vector_type(8))) short short8;   // 8 bf16 = 4 VGPRs
typedef __attribute__((ext_vector_type(4))) float float4v;  // MFMA accumulator

union frag_u { short8 v; u16 u[8]; };

__device__ inline u16 f2bf(float f) {
    unsigned u = __builtin_bit_cast(unsigned, f);
    unsigned r = (u + 0x7fffu + ((u >> 16) & 1u)) >> 16;
    return (u16)r;
}
__device__ inline float bf2f(u16 h) {
    unsigned u = ((unsigned)h) << 16;
    return __builtin_bit_cast(float, u);
}

// ---------------------------------------------------------------------------
// Prep: swizzle weights into MFMA B-fragment-ready bf16 layout.
// 128x128 W -> [cb 8][kk 4][quad 4][lan 16][j 8] u16 (16384)
//   element = W[k=kk*32+quad*8+j][n=cb*16+lan]
// Ww1 128x8 -> [kk 4][quad 4][lan 16][j 8] u16 (4096), zero for lan>=8
// ---------------------------------------------------------------------------
__global__ __launch_bounds__(256) void prep_w(
    const float* __restrict__ Wk, const float* __restrict__ Wv,
    const float* __restrict__ Wq, const float* __restrict__ Wp2,
    const float* __restrict__ Ww1, u16* __restrict__ dst)
{
    const int b = blockIdx.x, t = threadIdx.x;
    if (b < 4) {
        const float* W = b == 0 ? Wk : b == 1 ? Wv : b == 2 ? Wq : Wp2;
        u16* d = dst + b * 16384;
        for (int e = t; e < 16384; e += 256) {
            const int k = e >> 7, n = e & 127;
            const int cb = n >> 4, lan = n & 15;
            const int kk = k >> 5, quad = (k >> 3) & 3, j = k & 7;
            d[(((cb * 4 + kk) * 4 + quad) * 16 + lan) * 8 + j] = f2bf(W[e]);
        }
    } else {
        u16* d = dst + 4 * 16384;
        for (int e = t; e < 4096; e += 256) {
            const int j = e & 7, lan = (e >> 3) & 15;
            const int quad = (e >> 7) & 3, kk = e >> 9;
            const int k = kk * 32 + quad * 8 + j;
            d[e] = lan < 8 ? f2bf(Ww1[k * G + lan]) : (u16)0;
        }
    }
}

// ---------------------------------------------------------------------------
// Fused k,v projection. 64 rows/block, 4 waves. Coalesced stores via LDS Os.
// ---------------------------------------------------------------------------
__global__ __launch_bounds__(256) void proj_kv(
    const float* __restrict__ X,
    const u16* __restrict__ PWk, const float* __restrict__ bk,
    const float* __restrict__ gk, const float* __restrict__ betak,
    const u16* __restrict__ PWv, const float* __restrict__ bv,
    u16* __restrict__ kout, u16* __restrict__ vout)
{
    __shared__ u16 Xs[64 * 136];
    __shared__ u16 Os[64 * 136];
    const int t = threadIdx.x;
    const int w = t >> 6, l = t & 63;
    const int quad = l >> 4, lan = l & 15;
    const long long row0 = (long long)blockIdx.x * 64;

    // stage X tile -> bf16 LDS
    {
        const float4* Xv = (const float4*)(X + row0 * C);
#pragma unroll
        for (int i = 0; i < 8; i++) {
            const int e = t + 256 * i;
            const int r = e >> 5, c4 = e & 31;
            const float4 f = Xv[e];
            uint2 p;
            p.x = (unsigned)f2bf(f.x) | ((unsigned)f2bf(f.y) << 16);
            p.y = (unsigned)f2bf(f.z) | ((unsigned)f2bf(f.w) << 16);
            *(uint2*)(&Xs[r * 136 + c4 * 4]) = p;
        }
    }

    // B fragments: one dwordx4 per (w2, ct, kk)
    short8 Bf[2][2][4];
#pragma unroll
    for (int w2 = 0; w2 < 2; w2++) {
        const u16* P = w2 ? PWv : PWk;
#pragma unroll
        for (int ct = 0; ct < 2; ct++) {
            const int cb = w * 2 + ct;
#pragma unroll
            for (int kk = 0; kk < 4; kk++)
                Bf[w2][ct][kk] = *(const short8*)(P + (((cb * 4 + kk) * 4 + quad) * 16 + lan) * 8);
        }
    }
    __syncthreads();

    float4v acc[2][2][4];
#pragma unroll
    for (int w2 = 0; w2 < 2; w2++)
#pragma unroll
        for (int ct = 0; ct < 2; ct++)
#pragma unroll
            for (int rt = 0; rt < 4; rt++)
                acc[w2][ct][rt] = (float4v)0.f;

#pragma unroll
    for (int rt = 0; rt < 4; rt++) {
#pragma unroll
        for (int kk = 0; kk < 4; kk++) {
            const short8 A = *(const short8*)(&Xs[(rt * 16 + lan) * 136 + kk * 32 + quad * 8]);
#pragma unroll
            for (int w2 = 0; w2 < 2; w2++)
#pragma unroll
                for (int ct = 0; ct < 2; ct++)
                    acc[w2][ct][rt] = __builtin_amdgcn_mfma_f32_16x16x32_bf16(
                        A, Bf[w2][ct][kk], acc[w2][ct][rt], 0, 0, 0);
        }
    }

    // k epilogue: bn+relu -> Os -> coalesced store
#pragma unroll
    for (int ct = 0; ct < 2; ct++) {
        const int cg = w * 32 + ct * 16 + lan;
        const float bb = bk[cg];
        const float sc = gk[cg] * rsqrtf(1.f + EPS);
        const float sh = betak[cg];
#pragma unroll
        for (int rt = 0; rt < 4; rt++)
#pragma unroll
            for (int reg = 0; reg < 4; reg++) {
                float y = (acc[0][ct][rt][reg] + bb) * sc + sh;
                y = y > 0.f ? y : 0.f;
                Os[(rt * 16 + quad * 4 + reg) * 136 + cg] = f2bf(y);
            }
    }
    __syncthreads();
#pragma unroll
    for (int i = 0; i < 4; i++) {
        const int e = t + 256 * i;
        const int r = e >> 4, cc = (e & 15) * 8;
        *(short8*)(kout + (row0 + r) * C + cc) = *(const short8*)(&Os[r * 136 + cc]);
    }
    __syncthreads();

    // v epilogue: bias -> Os -> coalesced store
#pragma unroll
    for (int ct = 0; ct < 2; ct++) {
        const int cg = w * 32 + ct * 16 + lan;
        const float bb = bv[cg];
#pragma unroll
        for (int rt = 0; rt < 4; rt++)
#pragma unroll
            for (int reg = 0; reg < 4; reg++)
                Os[(rt * 16 + quad * 4 + reg) * 136 + cg] = f2bf(acc[1][ct][rt][reg] + bb);
    }
    __syncthreads();
#pragma unroll
    for (int i = 0; i < 4; i++) {
        const int e = t + 256 * i;
        const int r = e >> 4, cc = (e & 15) * 8;
        *(short8*)(vout + (row0 + r) * C + cc) = *(const short8*)(&Os[r * 136 + cc]);
    }
}

// ---------------------------------------------------------------------------
// Attention v4: QB=4 queries/block, q-projection fused (MFMA vs pWq).
// LDS 39936 B -> 4 blocks/CU.
// ---------------------------------------------------------------------------
__global__ __launch_bounds__(256) void attn4(
    const float* __restrict__ qfeat,  // M x C fp32
    const u16* __restrict__ kbuf, const u16* __restrict__ vbuf,
    const float* __restrict__ qcoord, const float* __restrict__ ccoord,
    const u16* __restrict__ PWq, const float* __restrict__ bq,
    const float* __restrict__ gq, const float* __restrict__ betaq,
    const float* __restrict__ Wp1, const float* __restrict__ bp1,
    const float* __restrict__ gp1, const float* __restrict__ betap1,
    const u16* __restrict__ PWp2, const float* __restrict__ bp2,
    const u16* __restrict__ PWw1, const float* __restrict__ bw1,
    const float* __restrict__ gw1, const float* __restrict__ betaw1,
    const float* __restrict__ Ww2, const float* __restrict__ bw2,
    const int* __restrict__ knn, float* __restrict__ out)
{
    __shared__ u16   fA[64 * 136];    // h1 (A-frag bf16), later val
    __shared__ u16   relB[64 * 136];  // xq staging, then peb/rel
    __shared__ float qs[QB * C];      // projected q (fp32)
    __shared__ float pxs[64], pys[64], pzs[64], mfs[64];
    __shared__ float wl[QB * 16 * G]; // hw -> logits -> softmax weights (in place)

    const int t = threadIdx.x;
    const int w = t >> 6, l = t & 63;
    const int quad = l >> 4, lan = l & 15;
    const int m0 = blockIdx.x * QB;

    // ---- prefetch k/v gathers (rows p*16+rsub, cols c8..c8+8) ----
    const int rsub = t >> 4;
    const int c8 = (t & 15) * 8;
    float mfr[4];
    frag_u kg[4], vg[4];
#pragma unroll
    for (int p = 0; p < 4; p++) {
        const int ii = knn[m0 * KNN + p * 16 + rsub];
        mfr[p] = ii >= 0 ? 1.f : 0.f;
        const int i0 = ii >= 0 ? ii : 0;
        kg[p].v = *(const short8*)(kbuf + (size_t)i0 * C + c8);
        vg[p].v = *(const short8*)(vbuf + (size_t)i0 * C + c8);
    }

    // ---- P0: stage query rows as zero-padded 16-row A-frag in relB; positions ----
    {
        frag_u z;
        if (rsub < QB) {
            const float4 f0 = *(const float4*)(qfeat + (size_t)(m0 + rsub) * C + c8);
            const float4 f1 = *(const float4*)(qfeat + (size_t)(m0 + rsub) * C + c8 + 4);
            z.u[0] = f2bf(f0.x); z.u[1] = f2bf(f0.y);
            z.u[2] = f2bf(f0.z); z.u[3] = f2bf(f0.w);
            z.u[4] = f2bf(f1.x); z.u[5] = f2bf(f1.y);
            z.u[6] = f2bf(f1.z); z.u[7] = f2bf(f1.w);
        } else {
            z.v = (short8)0;
        }
        *(short8*)(&relB[rsub * 136 + c8]) = z.v;
    }
    if (t < 64) {
        const int q = t >> 4;
        const int ii = knn[m0 * KNN + t];
        const float mf = ii >= 0 ? 1.f : 0.f;
        const int i0 = ii >= 0 ? ii : 0;
        mfs[t] = mf;
        pxs[t] = (ccoord[i0 * 3 + 0] - qcoord[(m0 + q) * 3 + 0]) * mf;
        pys[t] = (ccoord[i0 * 3 + 1] - qcoord[(m0 + q) * 3 + 1]) * mf;
        pzs[t] = (ccoord[i0 * 3 + 2] - qcoord[(m0 + q) * 3 + 2]) * mf;
    }
    __syncthreads();

    // ---- P1a: q = relu(bn(xq @ Wq + bq)) via MFMA -> qs ----
    {
        short8 Bq[2][4];
#pragma unroll
        for (int ct = 0; ct < 2; ct++) {
            const int cb = w * 2 + ct;
#pragma unroll
            for (int kk = 0; kk < 4; kk++)
                Bq[ct][kk] = *(const short8*)(PWq + (((cb * 4 + kk) * 4 + quad) * 16 + lan) * 8);
        }
        float4v aq[2];
        aq[0] = (float4v)0.f; aq[1] = (float4v)0.f;
#pragma unroll
        for (int kk = 0; kk < 4; kk++) {
            const short8 A = *(const short8*)(&relB[lan * 136 + kk * 32 + quad * 8]);
#pragma unroll
            for (int ct = 0; ct < 2; ct++)
                aq[ct] = __builtin_amdgcn_mfma_f32_16x16x32_bf16(A, Bq[ct][kk], aq[ct], 0, 0, 0);
        }
        if (quad == 0) {
#pragma unroll
            for (int ct = 0; ct < 2; ct++) {
                const int col = w * 32 + ct * 16 + lan;
                const float bb = bq[col];
                const float sc = gq[col] * rsqrtf(1.f + EPS);
                const float sh = betaq[col];
#pragma unroll
                for (int reg = 0; reg < 4; reg++) {
                    float y = (aq[ct][reg] + bb) * sc + sh;
                    qs[reg * C + col] = y > 0.f ? y : 0.f;
                }
            }
        }
    }

    // ---- P1b: h1 = relu(bn(pos @ Wp1 + bp1)) -> fA bf16 (A-frag layout) ----
    {
        const int c = t & 127, hh = t >> 7;
        const float w0 = Wp1[c], w1_ = Wp1[C + c], w2_ = Wp1[2 * C + c];
        const float sc = gp1[c] * rsqrtf(1.f + EPS);
        const float bb = bp1[c], sh = betap1[c];
#pragma unroll
        for (int r2 = 0; r2 < 32; r2++) {
            const int r = hh * 32 + r2;
            float y = fmaf(pxs[r], w0, fmaf(pys[r], w1_, fmaf(pzs[r], w2_, bb)));
            y = y * sc + sh;
            y = y > 0.f ? y : 0.f;
            fA[r * 136 + c] = f2bf(y);
        }
    }
    __syncthreads();

    // ---- P2: peb = h1 @ Wp2 (MFMA), scatter bf16 into relB ----
    {
        short8 Bf[2][4];
#pragma unroll
        for (int ct = 0; ct < 2; ct++) {
            const int cb = w * 2 + ct;
#pragma unroll
            for (int kk = 0; kk < 4; kk++)
                Bf[ct][kk] = *(const short8*)(PWp2 + (((cb * 4 + kk) * 4 + quad) * 16 + lan) * 8);
        }
        float4v acc[2][4];
#pragma unroll
        for (int ct = 0; ct < 2; ct++)
#pragma unroll
            for (int q = 0; q < 4; q++) acc[ct][q] = (float4v)0.f;

#pragma unroll
        for (int q = 0; q < 4; q++) {
#pragma unroll
            for (int kk = 0; kk < 4; kk++) {
                const short8 A = *(const short8*)(&fA[(q * 16 + lan) * 136 + kk * 32 + quad * 8]);
#pragma unroll
                for (int ct = 0; ct < 2; ct++)
                    acc[ct][q] = __builtin_amdgcn_mfma_f32_16x16x32_bf16(
                        A, Bf[ct][kk], acc[ct][q], 0, 0, 0);
            }
        }
        const float bb0 = bp2[w * 32 + lan];
        const float bb1 = bp2[w * 32 + 16 + lan];
#pragma unroll
        for (int ct = 0; ct < 2; ct++)
#pragma unroll
            for (int q = 0; q < 4; q++)
#pragma unroll
                for (int reg = 0; reg < 4; reg++)
                    relB[(q * 16 + quad * 4 + reg) * 136 + w * 32 + ct * 16 + lan] =
                        f2bf(acc[ct][q][reg] + (ct ? bb1 : bb0));
    }
    __syncthreads();

    // ---- P3: rel = kg*mf - q + peb (in place), val = vg*mf + peb -> fA ----
    {
#pragma unroll
        for (int p = 0; p < 4; p++) {
            const int r = p * 16 + rsub;
            const float mf = mfr[p];
            frag_u peb, relv, valv;
            peb.v = *(const short8*)(&relB[r * 136 + c8]);
#pragma unroll
            for (int j = 0; j < 8; j++) {
                const float pe = bf2f(peb.u[j]);
                const float qv = qs[p * C + c8 + j];
                relv.u[j] = f2bf(fmaf(bf2f(kg[p].u[j]), mf, pe - qv));
                valv.u[j] = f2bf(fmaf(bf2f(vg[p].u[j]), mf, pe));
            }
            *(short8*)(&relB[r * 136 + c8]) = relv.v;
            *(short8*)(&fA[r * 136 + c8])  = valv.v;
        }
    }
    __syncthreads();

    // ---- P4: hw = relu(bn(rel @ Ww1 + bw1)) via MFMA; wave w -> query w ----
    {
        short8 Bw[4];
#pragma unroll
        for (int kk = 0; kk < 4; kk++)
            Bw[kk] = *(const short8*)(PWw1 + ((kk * 4 + quad) * 16 + lan) * 8);
        float4v acc = (float4v)0.f;
#pragma unroll
        for (int kk = 0; kk < 4; kk++) {
            const short8 A = *(const short8*)(&relB[(w * 16 + lan) * 136 + kk * 32 + quad * 8]);
            acc = __builtin_amdgcn_mfma_f32_16x16x32_bf16(A, Bw[kk], acc, 0, 0, 0);
        }
        if (lan < G) {
            const int g = lan;
            const float sc = gw1[g] * rsqrtf(1.f + EPS);
            const float bb = bw1[g], sh = betaw1[g];
#pragma unroll
            for (int reg = 0; reg < 4; reg++) {
                const int j = quad * 4 + reg;
                float y = (acc[reg] + bb) * sc + sh;
                wl[w * 128 + j * 8 + g] = y > 0.f ? y : 0.f;
            }
        }
    }
    __syncthreads();

    // ---- P5: logits = hw @ Ww2 + bw2; softmax over neighbors; * mask (in place) ----
    if (t < QB * G) {
        const int q = t >> 3, g2 = t & 7;
        float w2c[G];
#pragma unroll
        for (int g = 0; g < G; g++) w2c[g] = Ww2[g * G + g2];
        const float bb = bw2[g2];
        float lg[KNN], mx = -1e30f;
#pragma unroll
        for (int j = 0; j < KNN; j++) {
            float a = bb;
#pragma unroll
            for (int g = 0; g < G; g++) a = fmaf(wl[q * 128 + j * 8 + g], w2c[g], a);
            lg[j] = a;
            mx = fmaxf(mx, a);
        }
        float sum = 0.f;
#pragma unroll
        for (int j = 0; j < KNN; j++) { lg[j] = __expf(lg[j] - mx); sum += lg[j]; }
        const float inv = 1.f / sum;
#pragma unroll
        for (int j = 0; j < KNN; j++)
            wl[q * 128 + j * 8 + g2] = lg[j] * inv * mfs[q * 16 + j];
    }
    __syncthreads();

    // ---- P6: out[q][c] = sum_j val[j][c] * w[j][c>>4] ----
#pragma unroll
    for (int i = 0; i < 2; i++) {
        const int e = t + 256 * i;
        const int q = e >> 7, c = e & 127, g = c >> 4;
        float a = 0.f;
#pragma unroll
        for (int j = 0; j < KNN; j++)
            a = fmaf(bf2f(fA[(q * 16 + j) * 136 + c]), wl[q * 128 + j * 8 + g], a);
        out[(size_t)(m0 + q) * C + c] = a;
    }
}

// ---------------------------------------------------------------------------
extern "C" void kernel_launch(void* const* d_in, const int* in_sizes, int n_in,
                              void* d_out, int out_size, void* d_ws, size_t ws_size,
                              hipStream_t stream)
{
    const float* query_feat    = (const float*)d_in[0];
    const float* context_feat  = (const float*)d_in[1];
    const float* query_coord   = (const float*)d_in[2];
    const float* context_coord = (const float*)d_in[3];
    const float* Wq    = (const float*)d_in[4];
    const float* bq    = (const float*)d_in[5];
    const float* gq    = (const float*)d_in[6];
    const float* betaq = (const float*)d_in[7];
    const float* Wk    = (const float*)d_in[8];
    const float* bk    = (const float*)d_in[9];
    const float* gk    = (const float*)d_in[10];
    const float* betak = (const float*)d_in[11];
    const float* Wv    = (const float*)d_in[12];
    const float* bv    = (const float*)d_in[13];
    const float* Wp1   = (const float*)d_in[14];
    const float* bp1   = (const float*)d_in[15];
    const float* gp1   = (const float*)d_in[16];
    const float* betap1= (const float*)d_in[17];
    const float* Wp2   = (const float*)d_in[18];
    const float* bp2   = (const float*)d_in[19];
    const float* Ww1   = (const float*)d_in[20];
    const float* bw1   = (const float*)d_in[21];
    const float* gw1   = (const float*)d_in[22];
    const float* betaw1= (const float*)d_in[23];
    const float* Ww2   = (const float*)d_in[24];
    const float* bw2   = (const float*)d_in[25];
    const int*   knn   = (const int*)d_in[26];

    const int M = in_sizes[0] / C;   // 16384
    const int N = in_sizes[1] / C;   // 131072

    // workspace: k | v (bf16) | prepped weights
    u16* kb = (u16*)d_ws;
    u16* vb = kb + (size_t)N * C;
    u16* pw = vb + (size_t)N * C;    // Wk,Wv,Wq,Wp2 (4*16384) + Ww1 (4096)
    u16* pWk  = pw;
    u16* pWv  = pw + 16384;
    u16* pWq  = pw + 2 * 16384;
    u16* pWp2 = pw + 3 * 16384;
    u16* pWw1 = pw + 4 * 16384;

    prep_w<<<5, 256, 0, stream>>>(Wk, Wv, Wq, Wp2, Ww1, pw);
    proj_kv<<<N / 64, 256, 0, stream>>>(context_feat, pWk, bk, gk, betak,
                                        pWv, bv, kb, vb);
    attn4<<<M / QB, 256, 0, stream>>>(query_feat, kb, vb, query_coord, context_coord,
                                      pWq, bq, gq, betaq,
                                      Wp1, bp1, gp1, betap1, pWp2, bp2,
                                      pWw1, bw1, gw1, betaw1, Ww2, bw2,
                                      knn, (float*)d_out);
}

// Round 5
// 225.483 us; speedup vs baseline: 1.0849x; 1.0849x over previous
//
#include <hip/hip_runtime.h>

#define C 128
#define G 8
#define KNN 16
#define QB 4
#define EPS 1e-5f

typedef unsigned short u16;
typedef __attribute__((ext_vector_type(8))) short short8;   // 8 bf16 = 4 VGPRs
typedef __attribute__((ext_vector_type(4))) float float4v;  // MFMA accumulator

union frag_u { short8 v; u16 u[8]; };

__device__ inline u16 f2bf(float f) {
    unsigned u = __builtin_bit_cast(unsigned, f);
    unsigned r = (u + 0x7fffu + ((u >> 16) & 1u)) >> 16;
    return (u16)r;
}
__device__ inline float bf2f(u16 h) {
    unsigned u = ((unsigned)h) << 16;
    return __builtin_bit_cast(float, u);
}

// ---------------------------------------------------------------------------
// Prep: swizzle weights into MFMA B-fragment-ready bf16 layout.
// 128x128 W -> [cb 8][kk 4][quad 4][lan 16][j 8] u16 (16384)
//   element = W[k=kk*32+quad*8+j][n=cb*16+lan]
// Ww1 128x8 -> [kk 4][quad 4][lan 16][j 8] u16 (4096), zero for lan>=8
// 17 blocks: 4 matrices x 4 quarters + 1 for Ww1.
// ---------------------------------------------------------------------------
__global__ __launch_bounds__(256) void prep_w(
    const float* __restrict__ Wk, const float* __restrict__ Wv,
    const float* __restrict__ Wq, const float* __restrict__ Wp2,
    const float* __restrict__ Ww1, u16* __restrict__ dst)
{
    const int b = blockIdx.x, t = threadIdx.x;
    if (b < 16) {
        const int mi = b >> 2, qt = b & 3;
        const float* W = mi == 0 ? Wk : mi == 1 ? Wv : mi == 2 ? Wq : Wp2;
        u16* d = dst + mi * 16384;
        for (int e = qt * 4096 + t; e < (qt + 1) * 4096; e += 256) {
            const int k = e >> 7, n = e & 127;
            const int cb = n >> 4, lan = n & 15;
            const int kk = k >> 5, quad = (k >> 3) & 3, j = k & 7;
            d[(((cb * 4 + kk) * 4 + quad) * 16 + lan) * 8 + j] = f2bf(W[e]);
        }
    } else {
        u16* d = dst + 4 * 16384;
        for (int e = t; e < 4096; e += 256) {
            const int j = e & 7, lan = (e >> 3) & 15;
            const int quad = (e >> 7) & 3, kk = e >> 9;
            const int k = kk * 32 + quad * 8 + j;
            d[e] = lan < 8 ? f2bf(Ww1[k * G + lan]) : (u16)0;
        }
    }
}

// ---------------------------------------------------------------------------
// Fused projections. Blocks [0, nkv): context rows -> k (bn+relu) and v.
// Blocks [nkv, nkv+nq): query rows -> q (bn+relu). 64 rows/block, 4 waves.
// Single LDS buffer: Xs holds A-tile, then reused as store-staging.
// v computed FIRST and parked bf16-packed in 16 VGPRs to cap register peak.
// ---------------------------------------------------------------------------
__global__ __launch_bounds__(256) void proj_all(
    const float* __restrict__ Xc, const float* __restrict__ Xq,
    const u16* __restrict__ PWk, const float* __restrict__ bk,
    const float* __restrict__ gk, const float* __restrict__ betak,
    const u16* __restrict__ PWv, const float* __restrict__ bv,
    const u16* __restrict__ PWq, const float* __restrict__ bq,
    const float* __restrict__ gq, const float* __restrict__ betaq,
    u16* __restrict__ kout, u16* __restrict__ vout, u16* __restrict__ qout,
    int nkv)
{
    __shared__ u16 Xs[64 * 136];
    const int t = threadIdx.x;
    const int w = t >> 6, l = t & 63;
    const int quad = l >> 4, lan = l & 15;
    const bool isq = (int)blockIdx.x >= nkv;
    const long long row0 = (long long)(isq ? blockIdx.x - nkv : blockIdx.x) * 64;
    const float* X = isq ? Xq : Xc;

    // stage X tile -> bf16 LDS
    {
        const float4* Xv = (const float4*)(X + row0 * C);
#pragma unroll
        for (int i = 0; i < 8; i++) {
            const int e = t + 256 * i;
            const int r = e >> 5, c4 = e & 31;
            const float4 f = Xv[e];
            uint2 p;
            p.x = (unsigned)f2bf(f.x) | ((unsigned)f2bf(f.y) << 16);
            p.y = (unsigned)f2bf(f.z) | ((unsigned)f2bf(f.w) << 16);
            *(uint2*)(&Xs[r * 136 + c4 * 4]) = p;
        }
    }
    __syncthreads();

    if (!isq) {
        // ---- v pass (plain bias), packed to bf16 in regs ----
        unsigned vp[2][4][2];
        {
            short8 Bf[2][4];
#pragma unroll
            for (int ct = 0; ct < 2; ct++) {
                const int cb = w * 2 + ct;
#pragma unroll
                for (int kk = 0; kk < 4; kk++)
                    Bf[ct][kk] = *(const short8*)(PWv + (((cb * 4 + kk) * 4 + quad) * 16 + lan) * 8);
            }
            float4v acc[2][4];
#pragma unroll
            for (int ct = 0; ct < 2; ct++)
#pragma unroll
                for (int rt = 0; rt < 4; rt++) acc[ct][rt] = (float4v)0.f;
#pragma unroll
            for (int rt = 0; rt < 4; rt++)
#pragma unroll
                for (int kk = 0; kk < 4; kk++) {
                    const short8 A = *(const short8*)(&Xs[(rt * 16 + lan) * 136 + kk * 32 + quad * 8]);
#pragma unroll
                    for (int ct = 0; ct < 2; ct++)
                        acc[ct][rt] = __builtin_amdgcn_mfma_f32_16x16x32_bf16(
                            A, Bf[ct][kk], acc[ct][rt], 0, 0, 0);
                }
#pragma unroll
            for (int ct = 0; ct < 2; ct++) {
                const float bb = bv[w * 32 + ct * 16 + lan];
#pragma unroll
                for (int rt = 0; rt < 4; rt++)
#pragma unroll
                    for (int h = 0; h < 2; h++)
                        vp[ct][rt][h] = (unsigned)f2bf(acc[ct][rt][2 * h] + bb)
                                      | ((unsigned)f2bf(acc[ct][rt][2 * h + 1] + bb) << 16);
            }
        }
        // ---- k pass (bn+relu) ----
        float4v acck[2][4];
        {
            short8 Bf[2][4];
#pragma unroll
            for (int ct = 0; ct < 2; ct++) {
                const int cb = w * 2 + ct;
#pragma unroll
                for (int kk = 0; kk < 4; kk++)
                    Bf[ct][kk] = *(const short8*)(PWk + (((cb * 4 + kk) * 4 + quad) * 16 + lan) * 8);
            }
#pragma unroll
            for (int ct = 0; ct < 2; ct++)
#pragma unroll
                for (int rt = 0; rt < 4; rt++) acck[ct][rt] = (float4v)0.f;
#pragma unroll
            for (int rt = 0; rt < 4; rt++)
#pragma unroll
                for (int kk = 0; kk < 4; kk++) {
                    const short8 A = *(const short8*)(&Xs[(rt * 16 + lan) * 136 + kk * 32 + quad * 8]);
#pragma unroll
                    for (int ct = 0; ct < 2; ct++)
                        acck[ct][rt] = __builtin_amdgcn_mfma_f32_16x16x32_bf16(
                            A, Bf[ct][kk], acck[ct][rt], 0, 0, 0);
                }
        }
        __syncthreads();   // all A-reads done; Xs reusable

        // k epilogue -> Xs -> coalesced store
#pragma unroll
        for (int ct = 0; ct < 2; ct++) {
            const int cg = w * 32 + ct * 16 + lan;
            const float bb = bk[cg];
            const float sc = gk[cg] * rsqrtf(1.f + EPS);
            const float sh = betak[cg];
#pragma unroll
            for (int rt = 0; rt < 4; rt++)
#pragma unroll
                for (int reg = 0; reg < 4; reg++) {
                    float y = (acck[ct][rt][reg] + bb) * sc + sh;
                    y = y > 0.f ? y : 0.f;
                    Xs[(rt * 16 + quad * 4 + reg) * 136 + cg] = f2bf(y);
                }
        }
        __syncthreads();
#pragma unroll
        for (int i = 0; i < 4; i++) {
            const int e = t + 256 * i;
            const int r = e >> 4, cc = (e & 15) * 8;
            *(short8*)(kout + (row0 + r) * C + cc) = *(const short8*)(&Xs[r * 136 + cc]);
        }
        __syncthreads();

        // v epilogue (unpack) -> Xs -> coalesced store
#pragma unroll
        for (int ct = 0; ct < 2; ct++) {
            const int cg = w * 32 + ct * 16 + lan;
#pragma unroll
            for (int rt = 0; rt < 4; rt++)
#pragma unroll
                for (int h = 0; h < 2; h++) {
                    Xs[(rt * 16 + quad * 4 + 2 * h) * 136 + cg]     = (u16)(vp[ct][rt][h] & 0xffffu);
                    Xs[(rt * 16 + quad * 4 + 2 * h + 1) * 136 + cg] = (u16)(vp[ct][rt][h] >> 16);
                }
        }
        __syncthreads();
#pragma unroll
        for (int i = 0; i < 4; i++) {
            const int e = t + 256 * i;
            const int r = e >> 4, cc = (e & 15) * 8;
            *(short8*)(vout + (row0 + r) * C + cc) = *(const short8*)(&Xs[r * 136 + cc]);
        }
    } else {
        // ---- q path: one output, bn+relu ----
        short8 Bf[2][4];
#pragma unroll
        for (int ct = 0; ct < 2; ct++) {
            const int cb = w * 2 + ct;
#pragma unroll
            for (int kk = 0; kk < 4; kk++)
                Bf[ct][kk] = *(const short8*)(PWq + (((cb * 4 + kk) * 4 + quad) * 16 + lan) * 8);
        }
        float4v acc[2][4];
#pragma unroll
        for (int ct = 0; ct < 2; ct++)
#pragma unroll
            for (int rt = 0; rt < 4; rt++) acc[ct][rt] = (float4v)0.f;
#pragma unroll
        for (int rt = 0; rt < 4; rt++)
#pragma unroll
            for (int kk = 0; kk < 4; kk++) {
                const short8 A = *(const short8*)(&Xs[(rt * 16 + lan) * 136 + kk * 32 + quad * 8]);
#pragma unroll
                for (int ct = 0; ct < 2; ct++)
                    acc[ct][rt] = __builtin_amdgcn_mfma_f32_16x16x32_bf16(
                        A, Bf[ct][kk], acc[ct][rt], 0, 0, 0);
            }
        __syncthreads();
#pragma unroll
        for (int ct = 0; ct < 2; ct++) {
            const int cg = w * 32 + ct * 16 + lan;
            const float bb = bq[cg];
            const float sc = gq[cg] * rsqrtf(1.f + EPS);
            const float sh = betaq[cg];
#pragma unroll
            for (int rt = 0; rt < 4; rt++)
#pragma unroll
                for (int reg = 0; reg < 4; reg++) {
                    float y = (acc[ct][rt][reg] + bb) * sc + sh;
                    y = y > 0.f ? y : 0.f;
                    Xs[(rt * 16 + quad * 4 + reg) * 136 + cg] = f2bf(y);
                }
        }
        __syncthreads();
#pragma unroll
        for (int i = 0; i < 4; i++) {
            const int e = t + 256 * i;
            const int r = e >> 4, cc = (e & 15) * 8;
            *(short8*)(qout + (row0 + r) * C + cc) = *(const short8*)(&Xs[r * 136 + cc]);
        }
    }
}

// ---------------------------------------------------------------------------
// Attention v5: QB=4 queries/block. SINGLE 64x136 bf16 LDS buffer holds
// h1 -> peb -> rel -> val in sequence; val parked in regs across P4.
// LDS 20480 B; gathers issued in P3 (no top prefetch) to cap register peak.
// ---------------------------------------------------------------------------
__global__ __launch_bounds__(256) void attn5(
    const u16* __restrict__ qbuf, const u16* __restrict__ kbuf,
    const u16* __restrict__ vbuf,
    const float* __restrict__ qcoord, const float* __restrict__ ccoord,
    const float* __restrict__ Wp1, const float* __restrict__ bp1,
    const float* __restrict__ gp1, const float* __restrict__ betap1,
    const u16* __restrict__ PWp2, const float* __restrict__ bp2,
    const u16* __restrict__ PWw1, const float* __restrict__ bw1,
    const float* __restrict__ gw1, const float* __restrict__ betaw1,
    const float* __restrict__ Ww2, const float* __restrict__ bw2,
    const int* __restrict__ knn, float* __restrict__ out)
{
    __shared__ u16   fA[64 * 136];    // h1 -> peb -> rel -> val
    __shared__ float pxs[64], pys[64], pzs[64];
    __shared__ int   idxs[64];        // raw knn (signed; <0 = padded)
    __shared__ float wl[QB * 16 * G]; // hw -> logits -> weights (in place)

    const int t = threadIdx.x;
    const int w = t >> 6, l = t & 63;
    const int quad = l >> 4, lan = l & 15;
    const int m0 = blockIdx.x * QB;
    const int rsub = t >> 4;
    const int c8 = (t & 15) * 8;

    // ---- P0: indices + relative positions ----
    if (t < 64) {
        const int q = t >> 4;
        const int ii = knn[(m0 + q) * KNN + (t & 15)];
        const float mf = ii >= 0 ? 1.f : 0.f;
        const int i0 = ii >= 0 ? ii : 0;
        idxs[t] = ii;
        pxs[t] = (ccoord[i0 * 3 + 0] - qcoord[(m0 + q) * 3 + 0]) * mf;
        pys[t] = (ccoord[i0 * 3 + 1] - qcoord[(m0 + q) * 3 + 1]) * mf;
        pzs[t] = (ccoord[i0 * 3 + 2] - qcoord[(m0 + q) * 3 + 2]) * mf;
    }
    __syncthreads();

    // ---- P1: h1 = relu(bn(pos @ Wp1 + bp1)) -> fA bf16 (A-frag layout) ----
    {
        const int c = t & 127, hh = t >> 7;
        const float w0 = Wp1[c], w1_ = Wp1[C + c], w2_ = Wp1[2 * C + c];
        const float sc = gp1[c] * rsqrtf(1.f + EPS);
        const float bb = bp1[c], sh = betap1[c];
#pragma unroll
        for (int r2 = 0; r2 < 32; r2++) {
            const int r = hh * 32 + r2;
            float y = fmaf(pxs[r], w0, fmaf(pys[r], w1_, fmaf(pzs[r], w2_, bb)));
            y = y * sc + sh;
            y = y > 0.f ? y : 0.f;
            fA[r * 136 + c] = f2bf(y);
        }
    }
    __syncthreads();

    // ---- P2: peb = h1 @ Wp2 (MFMA) ----
    float4v acc[2][4];
    {
        short8 Bf[2][4];
#pragma unroll
        for (int ct = 0; ct < 2; ct++) {
            const int cb = w * 2 + ct;
#pragma unroll
            for (int kk = 0; kk < 4; kk++)
                Bf[ct][kk] = *(const short8*)(PWp2 + (((cb * 4 + kk) * 4 + quad) * 16 + lan) * 8);
        }
#pragma unroll
        for (int ct = 0; ct < 2; ct++)
#pragma unroll
            for (int q = 0; q < 4; q++) acc[ct][q] = (float4v)0.f;
#pragma unroll
        for (int q = 0; q < 4; q++)
#pragma unroll
            for (int kk = 0; kk < 4; kk++) {
                const short8 A = *(const short8*)(&fA[(q * 16 + lan) * 136 + kk * 32 + quad * 8]);
#pragma unroll
                for (int ct = 0; ct < 2; ct++)
                    acc[ct][q] = __builtin_amdgcn_mfma_f32_16x16x32_bf16(
                        A, Bf[ct][kk], acc[ct][q], 0, 0, 0);
            }
    }
    __syncthreads();   // all h1 reads done

    // ---- P2b: scatter peb bf16 -> fA (in place of h1) ----
    {
        const float bb0 = bp2[w * 32 + lan];
        const float bb1 = bp2[w * 32 + 16 + lan];
#pragma unroll
        for (int ct = 0; ct < 2; ct++)
#pragma unroll
            for (int q = 0; q < 4; q++)
#pragma unroll
                for (int reg = 0; reg < 4; reg++)
                    fA[(q * 16 + quad * 4 + reg) * 136 + w * 32 + ct * 16 + lan] =
                        f2bf(acc[ct][q][reg] + (ct ? bb1 : bb0));
    }
    __syncthreads();

    // ---- P3: gather k/v/q; rel -> fA (in place); val -> regs ----
    short8 valr[4];
    {
#pragma unroll
        for (int p = 0; p < 4; p++) {
            const int r = p * 16 + rsub;
            const int ii = idxs[r];
            const float mf = ii >= 0 ? 1.f : 0.f;
            const size_t i0 = ii >= 0 ? ii : 0;
            frag_u kgv, vgv, qgv, peb, relv, valv;
            kgv.v = *(const short8*)(kbuf + i0 * C + c8);
            vgv.v = *(const short8*)(vbuf + i0 * C + c8);
            qgv.v = *(const short8*)(qbuf + (size_t)(m0 + p) * C + c8);
            peb.v = *(const short8*)(&fA[r * 136 + c8]);
#pragma unroll
            for (int j = 0; j < 8; j++) {
                const float pe = bf2f(peb.u[j]);
                relv.u[j] = f2bf(fmaf(bf2f(kgv.u[j]), mf, pe - bf2f(qgv.u[j])));
                valv.u[j] = f2bf(fmaf(bf2f(vgv.u[j]), mf, pe));
            }
            *(short8*)(&fA[r * 136 + c8]) = relv.v;   // exclusive slot: no barrier needed
            valr[p] = valv.v;
        }
    }
    __syncthreads();

    // ---- P4: hw = relu(bn(rel @ Ww1 + bw1)) via MFMA; wave w -> query w ----
    {
        short8 Bw[4];
#pragma unroll
        for (int kk = 0; kk < 4; kk++)
            Bw[kk] = *(const short8*)(PWw1 + ((kk * 4 + quad) * 16 + lan) * 8);
        float4v a4 = (float4v)0.f;
#pragma unroll
        for (int kk = 0; kk < 4; kk++) {
            const short8 A = *(const short8*)(&fA[(w * 16 + lan) * 136 + kk * 32 + quad * 8]);
            a4 = __builtin_amdgcn_mfma_f32_16x16x32_bf16(A, Bw[kk], a4, 0, 0, 0);
        }
        if (lan < G) {
            const int g = lan;
            const float sc = gw1[g] * rsqrtf(1.f + EPS);
            const float bb = bw1[g], sh = betaw1[g];
#pragma unroll
            for (int reg = 0; reg < 4; reg++) {
                const int j = quad * 4 + reg;
                float y = (a4[reg] + bb) * sc + sh;
                wl[w * 128 + j * 8 + g] = y > 0.f ? y : 0.f;
            }
        }
    }
    __syncthreads();   // all rel reads done; wl ready

    // ---- P4b: scatter val regs -> fA ----
#pragma unroll
    for (int p = 0; p < 4; p++)
        *(short8*)(&fA[(p * 16 + rsub) * 136 + c8]) = valr[p];

    // ---- P5: logits = hw @ Ww2 + bw2; softmax; * mask (wl in place, wave 0) ----
    if (t < QB * G) {
        const int q = t >> 3, g2 = t & 7;
        float w2c[G];
#pragma unroll
        for (int g = 0; g < G; g++) w2c[g] = Ww2[g * G + g2];
        const float bb = bw2[g2];
        float lg[KNN], mx = -1e30f;
#pragma unroll
        for (int j = 0; j < KNN; j++) {
            float a = bb;
#pragma unroll
            for (int g = 0; g < G; g++) a = fmaf(wl[q * 128 + j * 8 + g], w2c[g], a);
            lg[j] = a;
            mx = fmaxf(mx, a);
        }
        float sum = 0.f;
#pragma unroll
        for (int j = 0; j < KNN; j++) { lg[j] = __expf(lg[j] - mx); sum += lg[j]; }
        const float inv = 1.f / sum;
#pragma unroll
        for (int j = 0; j < KNN; j++) {
            const float mf = idxs[q * 16 + j] >= 0 ? 1.f : 0.f;
            wl[q * 128 + j * 8 + g2] = lg[j] * inv * mf;
        }
    }
    __syncthreads();

    // ---- P6: out[q][c] = sum_j val[j][c] * w[j][c>>4] ----
#pragma unroll
    for (int i = 0; i < 2; i++) {
        const int e = t + 256 * i;
        const int q = e >> 7, c = e & 127, g = c >> 4;
        float a = 0.f;
#pragma unroll
        for (int j = 0; j < KNN; j++)
            a = fmaf(bf2f(fA[(q * 16 + j) * 136 + c]), wl[q * 128 + j * 8 + g], a);
        out[(size_t)(m0 + q) * C + c] = a;
    }
}

// ---------------------------------------------------------------------------
extern "C" void kernel_launch(void* const* d_in, const int* in_sizes, int n_in,
                              void* d_out, int out_size, void* d_ws, size_t ws_size,
                              hipStream_t stream)
{
    const float* query_feat    = (const float*)d_in[0];
    const float* context_feat  = (const float*)d_in[1];
    const float* query_coord   = (const float*)d_in[2];
    const float* context_coord = (const float*)d_in[3];
    const float* Wq    = (const float*)d_in[4];
    const float* bq    = (const float*)d_in[5];
    const float* gq    = (const float*)d_in[6];
    const float* betaq = (const float*)d_in[7];
    const float* Wk    = (const float*)d_in[8];
    const float* bk    = (const float*)d_in[9];
    const float* gk    = (const float*)d_in[10];
    const float* betak = (const float*)d_in[11];
    const float* Wv    = (const float*)d_in[12];
    const float* bv    = (const float*)d_in[13];
    const float* Wp1   = (const float*)d_in[14];
    const float* bp1   = (const float*)d_in[15];
    const float* gp1   = (const float*)d_in[16];
    const float* betap1= (const float*)d_in[17];
    const float* Wp2   = (const float*)d_in[18];
    const float* bp2   = (const float*)d_in[19];
    const float* Ww1   = (const float*)d_in[20];
    const float* bw1   = (const float*)d_in[21];
    const float* gw1   = (const float*)d_in[22];
    const float* betaw1= (const float*)d_in[23];
    const float* Ww2   = (const float*)d_in[24];
    const float* bw2   = (const float*)d_in[25];
    const int*   knn   = (const int*)d_in[26];

    const int M = in_sizes[0] / C;   // 16384
    const int N = in_sizes[1] / C;   // 131072

    // workspace: k | v | q (bf16) | prepped weights
    u16* kb = (u16*)d_ws;
    u16* vb = kb + (size_t)N * C;
    u16* qb = vb + (size_t)N * C;
    u16* pw = qb + (size_t)M * C;    // Wk,Wv,Wq,Wp2 (4*16384) + Ww1 (4096)
    u16* pWk  = pw;
    u16* pWv  = pw + 16384;
    u16* pWq  = pw + 2 * 16384;
    u16* pWp2 = pw + 3 * 16384;
    u16* pWw1 = pw + 4 * 16384;

    prep_w<<<17, 256, 0, stream>>>(Wk, Wv, Wq, Wp2, Ww1, pw);
    proj_all<<<N / 64 + M / 64, 256, 0, stream>>>(
        context_feat, query_feat,
        pWk, bk, gk, betak, pWv, bv,
        pWq, bq, gq, betaq,
        kb, vb, qb, N / 64);
    attn5<<<M / QB, 256, 0, stream>>>(qb, kb, vb, query_coord, context_coord,
                                      Wp1, bp1, gp1, betap1, pWp2, bp2,
                                      pWw1, bw1, gw1, betaw1, Ww2, bw2,
                                      knn, (float*)d_out);
}

// Round 6
// 218.829 us; speedup vs baseline: 1.1179x; 1.0304x over previous
//
#include <hip/hip_runtime.h>

#define C 128
#define G 8
#define KNN 16
#define QB 4
#define EPS 1e-5f

typedef unsigned short u16;
typedef __attribute__((ext_vector_type(8))) short short8;   // 8 bf16 = 4 VGPRs
typedef __attribute__((ext_vector_type(4))) float float4v;  // MFMA accumulator

union frag_u { short8 v; u16 u[8]; };

__device__ inline u16 f2bf(float f) {
    unsigned u = __builtin_bit_cast(unsigned, f);
    unsigned r = (u + 0x7fffu + ((u >> 16) & 1u)) >> 16;
    return (u16)r;
}
__device__ inline float bf2f(u16 h) {
    unsigned u = ((unsigned)h) << 16;
    return __builtin_bit_cast(float, u);
}

// ---------------------------------------------------------------------------
// Prep: swizzle weights into MFMA B-frag bf16 layout.
//   128x128 W -> [cb 8][kk 4][quad 4][lan 16][j 8]; elem = W[kk*32+quad*8+j][cb*16+lan]
//   Ww1 (128x8) and Wp2' = Wp2@Ww1 (128x8) -> single-cb frag, zero for lan>=8.
//   cw1[g] = bp2 . Ww1[:,g]  (8 floats).
// 18 blocks: 16 = 4 matrices x 4 quarters, 1 = Ww1, 1 = Wp2' + cw1.
// ---------------------------------------------------------------------------
__global__ __launch_bounds__(256) void prep_w(
    const float* __restrict__ Wk, const float* __restrict__ Wv,
    const float* __restrict__ Wq, const float* __restrict__ Wp2,
    const float* __restrict__ Ww1, const float* __restrict__ bp2,
    u16* __restrict__ dst, float* __restrict__ cw1)
{
    const int b = blockIdx.x, t = threadIdx.x;
    if (b < 16) {
        const int mi = b >> 2, qt = b & 3;
        const float* W = mi == 0 ? Wk : mi == 1 ? Wv : mi == 2 ? Wq : Wp2;
        u16* d = dst + mi * 16384;
        for (int e = qt * 4096 + t; e < (qt + 1) * 4096; e += 256) {
            const int k = e >> 7, n = e & 127;
            const int cb = n >> 4, lan = n & 15;
            const int kk = k >> 5, quad = (k >> 3) & 3, j = k & 7;
            d[(((cb * 4 + kk) * 4 + quad) * 16 + lan) * 8 + j] = f2bf(W[e]);
        }
    } else if (b == 16) {
        u16* d = dst + 4 * 16384;
        for (int e = t; e < 4096; e += 256) {
            const int j = e & 7, lan = (e >> 3) & 15;
            const int quad = (e >> 7) & 3, kk = e >> 9;
            const int k = kk * 32 + quad * 8 + j;
            d[e] = lan < 8 ? f2bf(Ww1[k * G + lan]) : (u16)0;
        }
    } else {
        // Wp2' = Wp2 @ Ww1 -> B-frag; cw1 = bp2 @ Ww1
        u16* d = dst + 4 * 16384 + 4096;
        for (int e = t; e < 4096; e += 256) d[e] = 0;
        __syncthreads();
#pragma unroll
        for (int it = 0; it < 4; it++) {
            const int k = it * 32 + (t >> 3), g = t & 7;
            float a = 0.f;
            for (int i = 0; i < C; i++)
                a = fmaf(Wp2[k * C + i], Ww1[i * G + g], a);
            const int kk = k >> 5, quad = (k >> 3) & 3, j = k & 7;
            d[((kk * 4 + quad) * 16 + g) * 8 + j] = f2bf(a);
        }
        if (t < G) {
            float a = 0.f;
            for (int i = 0; i < C; i++) a = fmaf(bp2[i], Ww1[i * G + t], a);
            cw1[t] = a;
        }
    }
}

// ---------------------------------------------------------------------------
// Fused projections. Blocks [0,nkv): context -> v (NxC bf16) + K' = k@Ww1 (NxG).
// Blocks [nkv,..): query -> Q' = q@Ww1 (MxG). Full k and q never stored.
// ---------------------------------------------------------------------------
__global__ __launch_bounds__(256) void proj_all(
    const float* __restrict__ Xc, const float* __restrict__ Xq,
    const u16* __restrict__ PWk, const float* __restrict__ bk,
    const float* __restrict__ gk, const float* __restrict__ betak,
    const u16* __restrict__ PWv, const float* __restrict__ bv,
    const u16* __restrict__ PWq, const float* __restrict__ bq,
    const float* __restrict__ gq, const float* __restrict__ betaq,
    const u16* __restrict__ PWw1b,
    u16* __restrict__ vout, u16* __restrict__ Kp, u16* __restrict__ Qp,
    int nkv)
{
    __shared__ u16 Xs[64 * 136];
    const int t = threadIdx.x;
    const int w = t >> 6, l = t & 63;
    const int quad = l >> 4, lan = l & 15;
    const bool isq = (int)blockIdx.x >= nkv;
    const long long row0 = (long long)(isq ? blockIdx.x - nkv : blockIdx.x) * 64;
    const float* X = isq ? Xq : Xc;

    // stage X tile -> bf16 LDS
    {
        const float4* Xv = (const float4*)(X + row0 * C);
#pragma unroll
        for (int i = 0; i < 8; i++) {
            const int e = t + 256 * i;
            const int r = e >> 5, c4 = e & 31;
            const float4 f = Xv[e];
            uint2 p;
            p.x = (unsigned)f2bf(f.x) | ((unsigned)f2bf(f.y) << 16);
            p.y = (unsigned)f2bf(f.z) | ((unsigned)f2bf(f.w) << 16);
            *(uint2*)(&Xs[r * 136 + c4 * 4]) = p;
        }
    }
    __syncthreads();

    if (!isq) {
        // ---- v pass (bias only), packed bf16 in regs ----
        unsigned vp[2][4][2];
        {
            short8 Bf[2][4];
#pragma unroll
            for (int ct = 0; ct < 2; ct++) {
                const int cb = w * 2 + ct;
#pragma unroll
                for (int kk = 0; kk < 4; kk++)
                    Bf[ct][kk] = *(const short8*)(PWv + (((cb * 4 + kk) * 4 + quad) * 16 + lan) * 8);
            }
            float4v acc[2][4];
#pragma unroll
            for (int ct = 0; ct < 2; ct++)
#pragma unroll
                for (int rt = 0; rt < 4; rt++) acc[ct][rt] = (float4v)0.f;
#pragma unroll
            for (int rt = 0; rt < 4; rt++)
#pragma unroll
                for (int kk = 0; kk < 4; kk++) {
                    const short8 A = *(const short8*)(&Xs[(rt * 16 + lan) * 136 + kk * 32 + quad * 8]);
#pragma unroll
                    for (int ct = 0; ct < 2; ct++)
                        acc[ct][rt] = __builtin_amdgcn_mfma_f32_16x16x32_bf16(
                            A, Bf[ct][kk], acc[ct][rt], 0, 0, 0);
                }
#pragma unroll
            for (int ct = 0; ct < 2; ct++) {
                const float bb = bv[w * 32 + ct * 16 + lan];
#pragma unroll
                for (int rt = 0; rt < 4; rt++)
#pragma unroll
                    for (int h = 0; h < 2; h++)
                        vp[ct][rt][h] = (unsigned)f2bf(acc[ct][rt][2 * h] + bb)
                                      | ((unsigned)f2bf(acc[ct][rt][2 * h + 1] + bb) << 16);
            }
        }
        // ---- k pass (bn+relu), kept in regs ----
        float4v acck[2][4];
        {
            short8 Bf[2][4];
#pragma unroll
            for (int ct = 0; ct < 2; ct++) {
                const int cb = w * 2 + ct;
#pragma unroll
                for (int kk = 0; kk < 4; kk++)
                    Bf[ct][kk] = *(const short8*)(PWk + (((cb * 4 + kk) * 4 + quad) * 16 + lan) * 8);
            }
#pragma unroll
            for (int ct = 0; ct < 2; ct++)
#pragma unroll
                for (int rt = 0; rt < 4; rt++) acck[ct][rt] = (float4v)0.f;
#pragma unroll
            for (int rt = 0; rt < 4; rt++)
#pragma unroll
                for (int kk = 0; kk < 4; kk++) {
                    const short8 A = *(const short8*)(&Xs[(rt * 16 + lan) * 136 + kk * 32 + quad * 8]);
#pragma unroll
                    for (int ct = 0; ct < 2; ct++)
                        acck[ct][rt] = __builtin_amdgcn_mfma_f32_16x16x32_bf16(
                            A, Bf[ct][kk], acck[ct][rt], 0, 0, 0);
                }
        }
        __syncthreads();   // Xs A-reads done

        // k epilogue: bn+relu -> Xs (row-major bf16, A-frag-readable)
#pragma unroll
        for (int ct = 0; ct < 2; ct++) {
            const int cg = w * 32 + ct * 16 + lan;
            const float bb = bk[cg];
            const float sc = gk[cg] * rsqrtf(1.f + EPS);
            const float sh = betak[cg];
#pragma unroll
            for (int rt = 0; rt < 4; rt++)
#pragma unroll
                for (int reg = 0; reg < 4; reg++) {
                    float y = (acck[ct][rt][reg] + bb) * sc + sh;
                    y = y > 0.f ? y : 0.f;
                    Xs[(rt * 16 + quad * 4 + reg) * 136 + cg] = f2bf(y);
                }
        }
        __syncthreads();

        // K' = k @ Ww1 : wave w handles rows [16w,16w+16)
        {
            short8 Bw[4];
#pragma unroll
            for (int kk = 0; kk < 4; kk++)
                Bw[kk] = *(const short8*)(PWw1b + ((kk * 4 + quad) * 16 + lan) * 8);
            float4v ka = (float4v)0.f;
#pragma unroll
            for (int kk = 0; kk < 4; kk++) {
                const short8 A = *(const short8*)(&Xs[(w * 16 + lan) * 136 + kk * 32 + quad * 8]);
                ka = __builtin_amdgcn_mfma_f32_16x16x32_bf16(A, Bw[kk], ka, 0, 0, 0);
            }
            if (lan < G) {
#pragma unroll
                for (int reg = 0; reg < 4; reg++)
                    Kp[(row0 + w * 16 + quad * 4 + reg) * G + lan] = f2bf(ka[reg]);
            }
        }
        __syncthreads();   // Xs K'-reads done

        // v epilogue (unpack) -> Xs -> coalesced store
#pragma unroll
        for (int ct = 0; ct < 2; ct++) {
            const int cg = w * 32 + ct * 16 + lan;
#pragma unroll
            for (int rt = 0; rt < 4; rt++)
#pragma unroll
                for (int h = 0; h < 2; h++) {
                    Xs[(rt * 16 + quad * 4 + 2 * h) * 136 + cg]     = (u16)(vp[ct][rt][h] & 0xffffu);
                    Xs[(rt * 16 + quad * 4 + 2 * h + 1) * 136 + cg] = (u16)(vp[ct][rt][h] >> 16);
                }
        }
        __syncthreads();
#pragma unroll
        for (int i = 0; i < 4; i++) {
            const int e = t + 256 * i;
            const int r = e >> 4, cc = (e & 15) * 8;
            *(short8*)(vout + (row0 + r) * C + cc) = *(const short8*)(&Xs[r * 136 + cc]);
        }
    } else {
        // ---- q path: q = relu(bn(xq@Wq+bq)) in regs -> Xs -> Q' = q@Ww1 ----
        float4v acc[2][4];
        {
            short8 Bf[2][4];
#pragma unroll
            for (int ct = 0; ct < 2; ct++) {
                const int cb = w * 2 + ct;
#pragma unroll
                for (int kk = 0; kk < 4; kk++)
                    Bf[ct][kk] = *(const short8*)(PWq + (((cb * 4 + kk) * 4 + quad) * 16 + lan) * 8);
            }
#pragma unroll
            for (int ct = 0; ct < 2; ct++)
#pragma unroll
                for (int rt = 0; rt < 4; rt++) acc[ct][rt] = (float4v)0.f;
#pragma unroll
            for (int rt = 0; rt < 4; rt++)
#pragma unroll
                for (int kk = 0; kk < 4; kk++) {
                    const short8 A = *(const short8*)(&Xs[(rt * 16 + lan) * 136 + kk * 32 + quad * 8]);
#pragma unroll
                    for (int ct = 0; ct < 2; ct++)
                        acc[ct][rt] = __builtin_amdgcn_mfma_f32_16x16x32_bf16(
                            A, Bf[ct][kk], acc[ct][rt], 0, 0, 0);
                }
        }
        __syncthreads();
#pragma unroll
        for (int ct = 0; ct < 2; ct++) {
            const int cg = w * 32 + ct * 16 + lan;
            const float bb = bq[cg];
            const float sc = gq[cg] * rsqrtf(1.f + EPS);
            const float sh = betaq[cg];
#pragma unroll
            for (int rt = 0; rt < 4; rt++)
#pragma unroll
                for (int reg = 0; reg < 4; reg++) {
                    float y = (acc[ct][rt][reg] + bb) * sc + sh;
                    y = y > 0.f ? y : 0.f;
                    Xs[(rt * 16 + quad * 4 + reg) * 136 + cg] = f2bf(y);
                }
        }
        __syncthreads();
        {
            short8 Bw[4];
#pragma unroll
            for (int kk = 0; kk < 4; kk++)
                Bw[kk] = *(const short8*)(PWw1b + ((kk * 4 + quad) * 16 + lan) * 8);
            float4v qa = (float4v)0.f;
#pragma unroll
            for (int kk = 0; kk < 4; kk++) {
                const short8 A = *(const short8*)(&Xs[(w * 16 + lan) * 136 + kk * 32 + quad * 8]);
                qa = __builtin_amdgcn_mfma_f32_16x16x32_bf16(A, Bw[kk], qa, 0, 0, 0);
            }
            if (lan < G) {
#pragma unroll
                for (int reg = 0; reg < 4; reg++)
                    Qp[(row0 + w * 16 + quad * 4 + reg) * G + lan] = f2bf(qa[reg]);
            }
        }
    }
}

// ---------------------------------------------------------------------------
// Attention v6: gathers only v (256 B/row) and K' (16 B/row).
// Logits via linear decomposition: L = K'[idx]*mf - Q' + PEB' + cw1 + bw1.
// ---------------------------------------------------------------------------
__global__ __launch_bounds__(256) void attn6(
    const u16* __restrict__ vbuf, const u16* __restrict__ Kp,
    const u16* __restrict__ Qp,
    const float* __restrict__ qcoord, const float* __restrict__ ccoord,
    const float* __restrict__ Wp1, const float* __restrict__ bp1,
    const float* __restrict__ gp1, const float* __restrict__ betap1,
    const u16* __restrict__ PWp2, const float* __restrict__ bp2,
    const u16* __restrict__ PWp2pb, const float* __restrict__ cw1,
    const float* __restrict__ bw1,
    const float* __restrict__ gw1, const float* __restrict__ betaw1,
    const float* __restrict__ Ww2, const float* __restrict__ bw2,
    const int* __restrict__ knn, float* __restrict__ out)
{
    __shared__ u16   fA[64 * 136];    // h1 -> peb -> val
    __shared__ u16   kgs[64 * G];     // gathered K' rows (bf16)
    __shared__ float qps[QB * G];     // Q' rows (fp32)
    __shared__ float pebp[64 * G];    // PEB' (fp32)
    __shared__ float cw1s[G];
    __shared__ float pxs[64], pys[64], pzs[64];
    __shared__ int   idxs[64];
    __shared__ float wl[QB * 16 * G]; // hw -> weights (in place)

    const int t = threadIdx.x;
    const int w = t >> 6, l = t & 63;
    const int quad = l >> 4, lan = l & 15;
    const int m0 = blockIdx.x * QB;
    const int rsub = t >> 4;
    const int c8 = (t & 15) * 8;

    // ---- P0: v prefetch (regs), indices, positions, K'/Q'/cw1 to LDS ----
    float mfr[4];
    frag_u vg[4];
#pragma unroll
    for (int p = 0; p < 4; p++) {
        const int ii = knn[m0 * KNN + p * 16 + rsub];
        mfr[p] = ii >= 0 ? 1.f : 0.f;
        const size_t i0 = ii >= 0 ? ii : 0;
        vg[p].v = *(const short8*)(vbuf + i0 * C + c8);
    }
    if (t < 64) {
        const int q = t >> 4;
        const int ii = knn[m0 * KNN + t];
        const float mf = ii >= 0 ? 1.f : 0.f;
        const int i0 = ii >= 0 ? ii : 0;
        idxs[t] = ii;
        pxs[t] = (ccoord[i0 * 3 + 0] - qcoord[(m0 + q) * 3 + 0]) * mf;
        pys[t] = (ccoord[i0 * 3 + 1] - qcoord[(m0 + q) * 3 + 1]) * mf;
        pzs[t] = (ccoord[i0 * 3 + 2] - qcoord[(m0 + q) * 3 + 2]) * mf;
        *(short8*)(&kgs[t * G]) = *(const short8*)(Kp + (size_t)i0 * G);
    } else if (t < 68) {
        const int p = t - 64;
        frag_u qv;
        qv.v = *(const short8*)(Qp + (size_t)(m0 + p) * G);
#pragma unroll
        for (int j = 0; j < G; j++) qps[p * G + j] = bf2f(qv.u[j]);
    } else if (t < 76) {
        cw1s[t - 68] = cw1[t - 68];
    }
    __syncthreads();

    // ---- P1: h1 = relu(bn(pos @ Wp1 + bp1)) -> fA bf16 (A-frag layout) ----
    {
        const int c = t & 127, hh = t >> 7;
        const float w0 = Wp1[c], w1_ = Wp1[C + c], w2_ = Wp1[2 * C + c];
        const float sc = gp1[c] * rsqrtf(1.f + EPS);
        const float bb = bp1[c], sh = betap1[c];
#pragma unroll
        for (int r2 = 0; r2 < 32; r2++) {
            const int r = hh * 32 + r2;
            float y = fmaf(pxs[r], w0, fmaf(pys[r], w1_, fmaf(pzs[r], w2_, bb)));
            y = y * sc + sh;
            y = y > 0.f ? y : 0.f;
            fA[r * 136 + c] = f2bf(y);
        }
    }
    __syncthreads();

    // ---- P2: peb = h1 @ Wp2 (32 MFMA) + PEB' = h1 @ Wp2' (4 MFMA) ----
    float4v acc[2][4];
    float4v pp = (float4v)0.f;
    {
        short8 Bf[2][4];
#pragma unroll
        for (int ct = 0; ct < 2; ct++) {
            const int cb = w * 2 + ct;
#pragma unroll
            for (int kk = 0; kk < 4; kk++)
                Bf[ct][kk] = *(const short8*)(PWp2 + (((cb * 4 + kk) * 4 + quad) * 16 + lan) * 8);
        }
#pragma unroll
        for (int ct = 0; ct < 2; ct++)
#pragma unroll
            for (int q = 0; q < 4; q++) acc[ct][q] = (float4v)0.f;
#pragma unroll
        for (int q = 0; q < 4; q++)
#pragma unroll
            for (int kk = 0; kk < 4; kk++) {
                const short8 A = *(const short8*)(&fA[(q * 16 + lan) * 136 + kk * 32 + quad * 8]);
#pragma unroll
                for (int ct = 0; ct < 2; ct++)
                    acc[ct][q] = __builtin_amdgcn_mfma_f32_16x16x32_bf16(
                        A, Bf[ct][kk], acc[ct][q], 0, 0, 0);
            }
        // PEB': wave w -> rows [16w,16w+16)
#pragma unroll
        for (int kk = 0; kk < 4; kk++) {
            const short8 Bp = *(const short8*)(PWp2pb + ((kk * 4 + quad) * 16 + lan) * 8);
            const short8 A = *(const short8*)(&fA[(w * 16 + lan) * 136 + kk * 32 + quad * 8]);
            pp = __builtin_amdgcn_mfma_f32_16x16x32_bf16(A, Bp, pp, 0, 0, 0);
        }
    }
    __syncthreads();   // all h1 reads done

    // ---- P2b: scatter peb (bf16, in place) and PEB' (fp32) ----
    {
        const float bb0 = bp2[w * 32 + lan];
        const float bb1 = bp2[w * 32 + 16 + lan];
#pragma unroll
        for (int ct = 0; ct < 2; ct++)
#pragma unroll
            for (int q = 0; q < 4; q++)
#pragma unroll
                for (int reg = 0; reg < 4; reg++)
                    fA[(q * 16 + quad * 4 + reg) * 136 + w * 32 + ct * 16 + lan] =
                        f2bf(acc[ct][q][reg] + (ct ? bb1 : bb0));
        if (lan < G) {
#pragma unroll
            for (int reg = 0; reg < 4; reg++)
                pebp[(w * 16 + quad * 4 + reg) * G + lan] = pp[reg];
        }
    }
    __syncthreads();

    // ---- P3: val = vg*mf + peb -> fA (in place); logits -> wl ----
    {
#pragma unroll
        for (int p = 0; p < 4; p++) {
            const int r = p * 16 + rsub;
            const float mf = mfr[p];
            frag_u peb, valv;
            peb.v = *(const short8*)(&fA[r * 136 + c8]);
#pragma unroll
            for (int j = 0; j < 8; j++)
                valv.u[j] = f2bf(fmaf(bf2f(vg[p].u[j]), mf, bf2f(peb.u[j])));
            *(short8*)(&fA[r * 136 + c8]) = valv.v;   // exclusive slot
        }
    }
    if (t < 64) {
        const int q = t >> 4, j = t & 15;
        const float mf = idxs[t] >= 0 ? 1.f : 0.f;
#pragma unroll
        for (int g = 0; g < G; g++) {
            const float L = bf2f(kgs[t * G + g]) * mf - qps[q * G + g]
                          + pebp[t * G + g] + cw1s[g] + bw1[g];
            const float y = L * (gw1[g] * rsqrtf(1.f + EPS)) + betaw1[g];
            wl[q * 128 + j * G + g] = y > 0.f ? y : 0.f;
        }
    }
    __syncthreads();

    // ---- P5: logits = hw @ Ww2 + bw2; softmax; * mask (wl in place) ----
    if (t < QB * G) {
        const int q = t >> 3, g2 = t & 7;
        float w2c[G];
#pragma unroll
        for (int g = 0; g < G; g++) w2c[g] = Ww2[g * G + g2];
        const float bb = bw2[g2];
        float lg[KNN], mx = -1e30f;
#pragma unroll
        for (int j = 0; j < KNN; j++) {
            float a = bb;
#pragma unroll
            for (int g = 0; g < G; g++) a = fmaf(wl[q * 128 + j * 8 + g], w2c[g], a);
            lg[j] = a;
            mx = fmaxf(mx, a);
        }
        float sum = 0.f;
#pragma unroll
        for (int j = 0; j < KNN; j++) { lg[j] = __expf(lg[j] - mx); sum += lg[j]; }
        const float inv = 1.f / sum;
#pragma unroll
        for (int j = 0; j < KNN; j++) {
            const float mf = idxs[q * 16 + j] >= 0 ? 1.f : 0.f;
            wl[q * 128 + j * 8 + g2] = lg[j] * inv * mf;
        }
    }
    __syncthreads();

    // ---- P6: out[q][c] = sum_j val[j][c] * w[j][c>>4] ----
#pragma unroll
    for (int i = 0; i < 2; i++) {
        const int e = t + 256 * i;
        const int q = e >> 7, c = e & 127, g = c >> 4;
        float a = 0.f;
#pragma unroll
        for (int j = 0; j < KNN; j++)
            a = fmaf(bf2f(fA[(q * 16 + j) * 136 + c]), wl[q * 128 + j * 8 + g], a);
        out[(size_t)(m0 + q) * C + c] = a;
    }
}

// ---------------------------------------------------------------------------
extern "C" void kernel_launch(void* const* d_in, const int* in_sizes, int n_in,
                              void* d_out, int out_size, void* d_ws, size_t ws_size,
                              hipStream_t stream)
{
    const float* query_feat    = (const float*)d_in[0];
    const float* context_feat  = (const float*)d_in[1];
    const float* query_coord   = (const float*)d_in[2];
    const float* context_coord = (const float*)d_in[3];
    const float* Wq    = (const float*)d_in[4];
    const float* bq    = (const float*)d_in[5];
    const float* gq    = (const float*)d_in[6];
    const float* betaq = (const float*)d_in[7];
    const float* Wk    = (const float*)d_in[8];
    const float* bk    = (const float*)d_in[9];
    const float* gk    = (const float*)d_in[10];
    const float* betak = (const float*)d_in[11];
    const float* Wv    = (const float*)d_in[12];
    const float* bv    = (const float*)d_in[13];
    const float* Wp1   = (const float*)d_in[14];
    const float* bp1   = (const float*)d_in[15];
    const float* gp1   = (const float*)d_in[16];
    const float* betap1= (const float*)d_in[17];
    const float* Wp2   = (const float*)d_in[18];
    const float* bp2   = (const float*)d_in[19];
    const float* Ww1   = (const float*)d_in[20];
    const float* bw1   = (const float*)d_in[21];
    const float* gw1   = (const float*)d_in[22];
    const float* betaw1= (const float*)d_in[23];
    const float* Ww2   = (const float*)d_in[24];
    const float* bw2   = (const float*)d_in[25];
    const int*   knn   = (const int*)d_in[26];

    const int M = in_sizes[0] / C;   // 16384
    const int N = in_sizes[1] / C;   // 131072

    // workspace: v (N*C bf16) | K' (N*G bf16) | Q' (M*G bf16) | prepped weights | cw1
    u16* vb = (u16*)d_ws;
    u16* Kp = vb + (size_t)N * C;
    u16* Qp = Kp + (size_t)N * G;
    u16* pw = Qp + (size_t)M * G;
    u16* pWk    = pw;
    u16* pWv    = pw + 16384;
    u16* pWq    = pw + 2 * 16384;
    u16* pWp2   = pw + 3 * 16384;
    u16* pWw1b  = pw + 4 * 16384;
    u16* pWp2pb = pw + 4 * 16384 + 4096;
    float* cw1  = (float*)(pw + 4 * 16384 + 2 * 4096);

    prep_w<<<18, 256, 0, stream>>>(Wk, Wv, Wq, Wp2, Ww1, bp2, pw, cw1);
    proj_all<<<N / 64 + M / 64, 256, 0, stream>>>(
        context_feat, query_feat,
        pWk, bk, gk, betak, pWv, bv,
        pWq, bq, gq, betaq, pWw1b,
        vb, Kp, Qp, N / 64);
    attn6<<<M / QB, 256, 0, stream>>>(vb, Kp, Qp, query_coord, context_coord,
                                      Wp1, bp1, gp1, betap1, pWp2, bp2,
                                      pWp2pb, cw1, bw1, gw1, betaw1, Ww2, bw2,
                                      knn, (float*)d_out);
}